// Round 1
// baseline (665.445 us; speedup 1.0000x reference)
//
#include <hip/hip_runtime.h>

#define DD 64   // node embedding dim (fixed by problem)

// ---------------------------------------------------------------------------
// h_all[n - c0][r][d] = sum_k x[n][k] * W_rel[r][k][d]  for n in [c0, c1)
// One block = 256 threads (4 waves) handles 64 nodes for one relation r.
// Each lane keeps its W column (64 floats) in registers; x rows are broadcast
// from LDS via wave-uniform float4 reads -> FMA-bound inner loop.
// ---------------------------------------------------------------------------
__global__ __launch_bounds__(256) void k_transform(
    const float* __restrict__ x, const float* __restrict__ Wrel,
    float* __restrict__ h_all, int R, int c0, int c1)
{
    const int r     = blockIdx.y;
    const int gbase = blockIdx.x * 64;        // node offset within chunk
    const int nbase = c0 + gbase;             // global node base
    const int tid   = threadIdx.x;
    const int lane  = tid & 63;
    const int wv    = tid >> 6;
    const int nv    = min(64, c1 - nbase);    // valid nodes in this block

    __shared__ float xs[64 * DD];

    // stage x[nbase .. nbase+nv) into LDS (coalesced float4)
    {
        const float4* s4 = (const float4*)(x + (size_t)nbase * DD);
        float4* d4 = (float4*)xs;
        for (int i = tid; i < 64 * DD / 4; i += 256) {
            if ((i >> 4) < nv) d4[i] = s4[i];
        }
    }

    // per-lane W column in registers
    float w[DD];
    const float* Wr = Wrel + (size_t)r * DD * DD;
    #pragma unroll
    for (int k = 0; k < DD; ++k) w[k] = Wr[k * DD + lane];

    __syncthreads();

    // each wave handles 16 nodes, 2 at a time for ILP
    for (int ni = wv * 16; ni < wv * 16 + 16; ni += 2) {
        const float4* xr0 = (const float4*)(xs + (ni)     * DD);
        const float4* xr1 = (const float4*)(xs + (ni + 1) * DD);
        float acc0 = 0.f, acc1 = 0.f;
        #pragma unroll
        for (int k4 = 0; k4 < DD / 4; ++k4) {
            float4 a = xr0[k4];
            float4 b = xr1[k4];
            acc0 = fmaf(a.x, w[k4 * 4 + 0], acc0);
            acc1 = fmaf(b.x, w[k4 * 4 + 0], acc1);
            acc0 = fmaf(a.y, w[k4 * 4 + 1], acc0);
            acc1 = fmaf(b.y, w[k4 * 4 + 1], acc1);
            acc0 = fmaf(a.z, w[k4 * 4 + 2], acc0);
            acc1 = fmaf(b.z, w[k4 * 4 + 2], acc1);
            acc0 = fmaf(a.w, w[k4 * 4 + 3], acc0);
            acc1 = fmaf(b.w, w[k4 * 4 + 3], acc1);
        }
        if (ni < nv)
            h_all[(((size_t)(gbase + ni)) * R + r) * DD + lane] = acc0;
        if (ni + 1 < nv)
            h_all[(((size_t)(gbase + ni + 1)) * R + r) * DD + lane] = acc1;
    }
}

// ---------------------------------------------------------------------------
// out[n][d] = sum_k x[n][k] * W_root[k][d] + bias[d]   (overwrites d_out base)
// ---------------------------------------------------------------------------
__global__ __launch_bounds__(256) void k_root(
    const float* __restrict__ x, const float* __restrict__ Wroot,
    const float* __restrict__ bias, float* __restrict__ out, int N)
{
    const int nbase = blockIdx.x * 64;
    const int tid   = threadIdx.x;
    const int lane  = tid & 63;
    const int wv    = tid >> 6;
    const int nv    = min(64, N - nbase);

    __shared__ float xs[64 * DD];
    {
        const float4* s4 = (const float4*)(x + (size_t)nbase * DD);
        float4* d4 = (float4*)xs;
        for (int i = tid; i < 64 * DD / 4; i += 256) {
            if ((i >> 4) < nv) d4[i] = s4[i];
        }
    }

    float w[DD];
    #pragma unroll
    for (int k = 0; k < DD; ++k) w[k] = Wroot[k * DD + lane];
    const float bl = bias[lane];

    __syncthreads();

    for (int ni = wv * 16; ni < wv * 16 + 16; ni += 2) {
        const float4* xr0 = (const float4*)(xs + (ni)     * DD);
        const float4* xr1 = (const float4*)(xs + (ni + 1) * DD);
        float acc0 = 0.f, acc1 = 0.f;
        #pragma unroll
        for (int k4 = 0; k4 < DD / 4; ++k4) {
            float4 a = xr0[k4];
            float4 b = xr1[k4];
            acc0 = fmaf(a.x, w[k4 * 4 + 0], acc0);
            acc1 = fmaf(b.x, w[k4 * 4 + 0], acc1);
            acc0 = fmaf(a.y, w[k4 * 4 + 1], acc0);
            acc1 = fmaf(b.y, w[k4 * 4 + 1], acc1);
            acc0 = fmaf(a.z, w[k4 * 4 + 2], acc0);
            acc1 = fmaf(b.z, w[k4 * 4 + 2], acc1);
            acc0 = fmaf(a.w, w[k4 * 4 + 3], acc0);
            acc1 = fmaf(b.w, w[k4 * 4 + 3], acc1);
        }
        if (ni < nv)     out[((size_t)(nbase + ni))     * DD + lane] = acc0 + bl;
        if (ni + 1 < nv) out[((size_t)(nbase + ni + 1)) * DD + lane] = acc1 + bl;
    }
}

// ---------------------------------------------------------------------------
// cnt[dst * R + rel] += 1 per edge
// ---------------------------------------------------------------------------
__global__ void k_count(const int* __restrict__ ei, const int* __restrict__ et,
                        int* __restrict__ cnt, int E, int R)
{
    int e = blockIdx.x * blockDim.x + threadIdx.x;
    if (e < E) {
        int dst = ei[E + e];
        int r   = et[e];
        atomicAdd(&cnt[(size_t)dst * R + r], 1);
    }
}

// ---------------------------------------------------------------------------
// One wave per edge: out[dst][d] += h_all[src-c0][rel][d] / max(cnt,1)
// Only edges whose src lies in the current chunk [c0, c1).
// ---------------------------------------------------------------------------
__global__ __launch_bounds__(256) void k_scatter(
    const int* __restrict__ ei, const int* __restrict__ et,
    const int* __restrict__ cnt, const float* __restrict__ h_all,
    float* __restrict__ out, int E, int R, int c0, int c1)
{
    const int e = blockIdx.x * 4 + (threadIdx.x >> 6);
    if (e >= E) return;
    const int lane = threadIdx.x & 63;

    const int src = ei[e];
    if (src < c0 || src >= c1) return;
    const int dst = ei[E + e];
    const int r   = et[e];

    const float c  = (float)cnt[(size_t)dst * R + r];
    const float nm = 1.0f / fmaxf(c, 1.0f);
    const float v  = h_all[(((size_t)(src - c0)) * R + r) * DD + lane] * nm;
    atomicAdd(out + (size_t)dst * DD + lane, v);
}

// ---------------------------------------------------------------------------
// echo edge_index / edge_type into d_out tail as float
// ---------------------------------------------------------------------------
__global__ void k_echo(const int* __restrict__ ei, const int* __restrict__ et,
                       float* __restrict__ out_ei, float* __restrict__ out_et,
                       int E)
{
    int i = blockIdx.x * 256 + threadIdx.x;
    if (i < 2 * E) out_ei[i] = (float)ei[i];
    if (i < E)     out_et[i] = (float)et[i];
}

extern "C" void kernel_launch(void* const* d_in, const int* in_sizes, int n_in,
                              void* d_out, int out_size, void* d_ws, size_t ws_size,
                              hipStream_t stream)
{
    const float* x     = (const float*)d_in[0];
    const int*   ei    = (const int*)d_in[1];
    const int*   et    = (const int*)d_in[2];
    const float* Wrel  = (const float*)d_in[3];
    const float* Wroot = (const float*)d_in[4];
    const float* bias  = (const float*)d_in[5];

    const int N = in_sizes[0] / DD;
    const int E = in_sizes[2];
    const int R = in_sizes[3] / (DD * DD);   // 8

    float* out    = (float*)d_out;
    float* out_ei = out + (size_t)N * DD;
    float* out_et = out_ei + (size_t)2 * E;

    // workspace layout: [cnt (N*R int)] [h_all chunk (chunk_nodes*R*DD float)]
    int* cnt = (int*)d_ws;
    size_t cnt_bytes = (((size_t)N * R * sizeof(int)) + 255) & ~(size_t)255;
    float* h_all = (float*)((char*)d_ws + cnt_bytes);
    size_t h_avail = (ws_size > cnt_bytes) ? (ws_size - cnt_bytes) : 0;

    size_t per_node = (size_t)R * DD * sizeof(float);   // 2 KB
    int chunk_nodes = (int)((h_avail / per_node) & ~(size_t)63);
    if (chunk_nodes > N) chunk_nodes = (N + 63) & ~63;
    if (chunk_nodes < 64) chunk_nodes = 64;             // assume ws is sane

    hipMemsetAsync(cnt, 0, (size_t)N * R * sizeof(int), stream);

    // base: out = x @ W_root + bias
    k_root<<<dim3((N + 63) / 64), 256, 0, stream>>>(x, Wroot, bias, out, N);

    // per-(dst, rel) counts
    k_count<<<dim3((E + 255) / 256), 256, 0, stream>>>(ei, et, cnt, E, R);

    // chunked per-relation transform + edge scatter
    for (int c0 = 0; c0 < N; c0 += chunk_nodes) {
        int c1 = min(N, c0 + chunk_nodes);
        int ngroups = (c1 - c0 + 63) / 64;
        k_transform<<<dim3(ngroups, R), 256, 0, stream>>>(x, Wrel, h_all, R, c0, c1);
        k_scatter<<<dim3((E + 3) / 4), 256, 0, stream>>>(ei, et, cnt, h_all, out,
                                                         E, R, c0, c1);
    }

    // echo edge_index / edge_type
    k_echo<<<dim3((2 * E + 255) / 256), 256, 0, stream>>>(ei, et, out_ei, out_et, E);
}